// Round 12
// baseline (231.068 us; speedup 1.0000x reference)
//
#include <hip/hip_runtime.h>
#include <math.h>

#define B_   256
#define S_   512
#define NQ_  1000
#define MEM_ 20
#define DK_  50
#define DV_  200
#define FC_  50
#define CHK  8              // r7: 16->8 — halves ABu/Mv0p/prefix glue traffic
#define CLEN (S_/CHK)       // 64 steps per chunk
#define HLEN 32             // MFMA half-chunk (rows per MFMA phase)
#define NKS  7              // K-steps for MFMA (K = 224 = 200 + 24 zero)
#define XS_STRIDE 232       // LDS row stride (16B-aligned, conflict-light — validated)
#define CORR_STRIDE 12      // uints per corr row (10 used + 2 pad -> 48B)
#define NB_EAMM  252        // r12: EA as MFMA GEMM — 63 row-tiles(32) x 4 col-tiles(64)
#define NB_CORR  4
#define NB_WPACK 7
#define NB_HQ    251
#define PREP_BLOCKS (NB_EAMM+NB_CORR+NB_WPACK+NB_HQ)  // 514
#define MM_BLOCKS (B_*CHK)        // 2048
#define SCANA_BLOCKS (B_*(CHK-1)) // 1792

typedef __attribute__((ext_vector_type(8))) short bf16x8_t;
typedef __attribute__((ext_vector_type(8))) _Float16 f16x8_t;
typedef __attribute__((ext_vector_type(4))) float f32x4_t;
typedef __attribute__((ext_vector_type(2))) _Float16 f16x2_t;

static __device__ __forceinline__ f16x2_t h2(unsigned u){ return __builtin_bit_cast(f16x2_t, u); }
static __device__ __forceinline__ unsigned h2u(f16x2_t v){ return __builtin_bit_cast(unsigned, v); }
static __device__ __forceinline__ unsigned packh2(float x, float y){
  unsigned short bx = __builtin_bit_cast(unsigned short, (_Float16)x);
  unsigned short by = __builtin_bit_cast(unsigned short, (_Float16)y);
  return (unsigned)bx | ((unsigned)by << 16);
}
static __device__ __forceinline__ f16x2_t pkfma16(f16x2_t a, f16x2_t b, f16x2_t c){
  return __builtin_elementwise_fma(a, b, c);     // -> v_pk_fma_f16 (full rate)
}
static __device__ __forceinline__ f16x2_t splat_l(f16x2_t p){ return __builtin_shufflevector(p, p, 0, 0); }
static __device__ __forceinline__ f16x2_t splat_h(f16x2_t p){ return __builtin_shufflevector(p, p, 1, 1); }

static __device__ __forceinline__ unsigned short f2bf(float f){
  unsigned u = __float_as_uint(f);
  unsigned r = u + 0x7fffu + ((u >> 16) & 1u);   // round-to-nearest-even
  return (unsigned short)(r >> 16);
}
static __device__ __forceinline__ float ftanh(float x){
  float e = __expf(2.f*x);
  return 1.f - 2.f*__builtin_amdgcn_rcpf(e+1.f);
}
static __device__ __forceinline__ float fsigm(float x){
  return __builtin_amdgcn_rcpf(1.f+__expf(-x));
}

// K0: prep — [0,252): eaTab via MFMA GEMM (r12: the EA branch's 200-iter
// serial FMA loop hit the same unexplained per-step floor as the scans —
// two pipeline fixes flat. It IS a GEMM: [2001x200]@[200x200] x2 — so run
// it on the matrix cores. f16 inputs (11-bit mantissa, err ~1e-5 << the 2^-8
// absmax quantum). A/B/C lane layouts copied from the validated k_scan_mm /
// WpFrag patterns; stride-232 LDS (16B-aligned).)
// [252,256): corrH; [256,263): WpFrag+pwPad; [263,514): hq.
__global__ __launch_bounds__(256) void k_prep1(
    const float* __restrict__ qaw,
    const float* __restrict__ ew, const float* __restrict__ eb,
    const float* __restrict__ aw, const float* __restrict__ ab,
    unsigned* __restrict__ eaTab,
    const float* __restrict__ qw, const float* __restrict__ mk,
    unsigned* __restrict__ corrH,
    const float* __restrict__ rw, const float* __restrict__ rb,
    const float* __restrict__ pw,
    unsigned short* __restrict__ WpFrag, float* __restrict__ pwPad,
    float* __restrict__ hq){
  __shared__ __align__(16) _Float16 sh[(32+64)*232];   // 44,544 B -> 3 blocks/CU
  int blk = blockIdx.x;
  int td = threadIdx.x;
  if(blk < NB_EAMM){
    _Float16* qaL = sh;            // [32][224] logical, stride 232
    _Float16* bL  = sh + 32*232;   // [64][224] logical (transposed W tile), stride 232
    const int rt = blk >> 2, ct = blk & 3;
    const int row0 = rt*32, n0 = ct*64;

    // stage qa tile (A operand): coalesced in k, zero-pad k>=200 / rows>2000
    #pragma unroll
    for(int i=0;i<28;++i){                 // 32*224/256
      int idx = td + 256*i;
      int m = (int)(((unsigned)idx*37450u)>>23);   // idx/224 (verified to 7167)
      int k = idx - m*224;
      int row = row0 + m;
      float v = (k < DV_ && row <= 2*NQ_) ? qaw[(size_t)row*DV_ + k] : 0.f;
      qaL[m*232 + k] = (_Float16)v;
    }
    __syncthreads();

    const int lane = td & 63, wave = td >> 6;
    const int col = lane & 15, quad = lane >> 4;
    const int mt = wave >> 1;              // 0..1 (m-tile of 16)
    const int ntA = (wave & 1)*2;          // first of two n-tiles {0,2}

    f16x8_t afr[NKS];
    #pragma unroll
    for(int ks=0;ks<NKS;++ks)
      afr[ks] = *(const f16x8_t*)(qaL + (mt*16+col)*232 + quad*8 + ks*32);

    // ---- E GEMM: stage erase_w transposed, accumulate ----
    #pragma unroll
    for(int i=0;i<56;++i){                 // 224*64/256; k=idx>>6, n=idx&63
      int idx = td + 256*i;
      int k = idx >> 6, n = idx & 63;
      int ng = n0 + n;
      float v = (k < DV_ && ng < DV_) ? ew[(size_t)k*DV_ + ng] : 0.f;
      bL[n*232 + k] = (_Float16)v;
    }
    __syncthreads();
    f32x4_t accE[2];
    accE[0] = (f32x4_t){0.f,0.f,0.f,0.f};
    accE[1] = (f32x4_t){0.f,0.f,0.f,0.f};
    #pragma unroll
    for(int ks=0;ks<NKS;++ks){
      f16x8_t b0 = *(const f16x8_t*)(bL + ((ntA+0)*16+col)*232 + quad*8 + ks*32);
      f16x8_t b1 = *(const f16x8_t*)(bL + ((ntA+1)*16+col)*232 + quad*8 + ks*32);
      accE[0] = __builtin_amdgcn_mfma_f32_16x16x32_f16(afr[ks], b0, accE[0], 0, 0, 0);
      accE[1] = __builtin_amdgcn_mfma_f32_16x16x32_f16(afr[ks], b1, accE[1], 0, 0, 0);
    }
    __syncthreads();   // drain reads before overwriting bL

    // ---- A GEMM: restage add_w into the same buffer ----
    #pragma unroll
    for(int i=0;i<56;++i){
      int idx = td + 256*i;
      int k = idx >> 6, n = idx & 63;
      int ng = n0 + n;
      float v = (k < DV_ && ng < DV_) ? aw[(size_t)k*DV_ + ng] : 0.f;
      bL[n*232 + k] = (_Float16)v;
    }
    __syncthreads();
    f32x4_t accA[2];
    accA[0] = (f32x4_t){0.f,0.f,0.f,0.f};
    accA[1] = (f32x4_t){0.f,0.f,0.f,0.f};
    #pragma unroll
    for(int ks=0;ks<NKS;++ks){
      f16x8_t b0 = *(const f16x8_t*)(bL + ((ntA+0)*16+col)*232 + quad*8 + ks*32);
      f16x8_t b1 = *(const f16x8_t*)(bL + ((ntA+1)*16+col)*232 + quad*8 + ks*32);
      accA[0] = __builtin_amdgcn_mfma_f32_16x16x32_f16(afr[ks], b0, accA[0], 0, 0, 0);
      accA[1] = __builtin_amdgcn_mfma_f32_16x16x32_f16(afr[ks], b1, accA[1], 0, 0, 0);
    }

    // epilogue: bias + sigmoid/tanh + packed f16 store (C/D map: n=lane&15,
    // m=quad*4+reg — same as k_scan_mm's validated epilogue)
    #pragma unroll
    for(int j=0;j<2;++j){
      int ng = n0 + (ntA+j)*16 + col;
      if(ng < DV_){
        float ebv = eb[ng], abv = ab[ng];
        #pragma unroll
        for(int reg=0;reg<4;++reg){
          int row = row0 + mt*16 + quad*4 + reg;
          if(row <= 2*NQ_){
            float e = fsigm(accE[j][reg] + ebv);
            float a = ftanh(accA[j][reg] + abv);
            eaTab[(size_t)row*DV_ + ng] = packh2(e, a);
          }
        }
      }
    }
  } else if(blk < NB_EAMM+NB_CORR){
    int q = (blk-NB_EAMM)*256 + td;
    if(q > NQ_) return;
    float qv[DK_];
    #pragma unroll
    for(int j=0;j<DK_;++j) qv[j] = qw[q*DK_+j];
    float s[MEM_]; float mx = -1e30f;
    #pragma unroll
    for(int m=0;m<MEM_;++m){
      float acc = 0.f;
      #pragma unroll
      for(int j=0;j<DK_;++j) acc = fmaf(qv[j], mk[m*DK_+j], acc);
      s[m] = acc; mx = fmaxf(mx, acc);
    }
    float sum = 0.f;
    #pragma unroll
    for(int m=0;m<MEM_;++m){ s[m] = __expf(s[m]-mx); sum += s[m]; }
    float inv = __builtin_amdgcn_rcpf(sum);
    #pragma unroll
    for(int i=0;i<MEM_/2;++i)
      corrH[q*CORR_STRIDE+i] = packh2(s[2*i]*inv, s[2*i+1]*inv);
  } else if(blk < NB_EAMM+NB_CORR+NB_WPACK){
    int ks = blk - (NB_EAMM+NB_CORR);
    int nt = td >> 6;
    int lane = td & 63;
    int quad = lane >> 4, col = lane & 15;
    int n = nt*16 + col;
    unsigned short tmp[8];
    #pragma unroll
    for(int j=0;j<8;++j){
      int k = ks*32 + quad*8 + j;
      tmp[j] = (k < DV_ && n < FC_) ? f2bf(rw[k*FC_+n]) : (unsigned short)0;
    }
    uint4* dst = reinterpret_cast<uint4*>(WpFrag + ((size_t)(ks*4+nt)*64 + lane)*8);
    *dst = *reinterpret_cast<const uint4*>(tmp);
    if(ks == 0 && td < 64)
      pwPad[td] = (td < FC_) ? pw[td] : 0.f;
  } else {
    int idx = (blk-(NB_EAMM+NB_CORR+NB_WPACK))*256 + td;
    int q = idx >> 6, n = idx & 63;
    if(q > NQ_) return;
    float v = 0.f;
    if(n < FC_){
      float acc = rb[n];
      #pragma unroll
      for(int j=0;j<DK_;++j)
        acc = fmaf(qw[q*DK_+j], rw[(DV_+j)*FC_+n], acc);
      v = acc;
    }
    hq[q*64+n] = v;
  }
}

// K1: phase 1 — per-chunk affine (A,B) over 64 steps (CHK=8). Per-step code
// identical to the validated r5 loop. Scan state dies at kernel end — no
// lifetime overlap, no scratch.
__global__ __launch_bounds__(256,8) void k_scanA(const int* __restrict__ qd,
    const int* __restrict__ qad,
    const unsigned* __restrict__ corrH,
    const unsigned* __restrict__ eaTab,
    unsigned* __restrict__ ABu){
  const int blk = blockIdx.x;
  const int b = blk / (CHK-1), c = blk % (CHK-1);
  const int d = threadIdx.x;
  const int dc = (d < DV_) ? d : DV_-1;
  const bool act = (d < DV_);
  const int* __restrict__ qp  = qd  + b*S_ + c*CLEN;
  const int* __restrict__ qap = qad + b*S_ + c*CLEN;

  const f16x2_t one2h = {(_Float16)1.f, (_Float16)1.f};
  f16x2_t A2[MEM_/2], B2[MEM_/2];
  #pragma unroll
  for(int i=0;i<MEM_/2;++i){ A2[i] = one2h; B2[i] = (f16x2_t){(_Float16)0.f,(_Float16)0.f}; }

  unsigned ea0 = eaTab[(size_t)qap[0]*DV_ + dc];
  unsigned ea1 = eaTab[(size_t)qap[1]*DV_ + dc];
  unsigned ea2 = eaTab[(size_t)qap[2]*DV_ + dc];
  int qa3 = qap[3], qa4 = qap[4], qa5 = qap[5];
  int s0 = __builtin_amdgcn_readfirstlane(qp[0]);
  int s1 = __builtin_amdgcn_readfirstlane(qp[1]);
  const unsigned* c0p = corrH + s0*CORR_STRIDE;
  uint4 ca0 = *(const uint4*)(c0p); uint4 cb0 = *(const uint4*)(c0p+4); uint2 cc0 = *(const uint2*)(c0p+8);
  const unsigned* c1p = corrH + s1*CORR_STRIDE;
  uint4 ca1 = *(const uint4*)(c1p); uint4 cb1 = *(const uint4*)(c1p+4); uint2 cc1 = *(const uint2*)(c1p+8);
  int qn2 = qp[2], qn3 = qp[3];

  #pragma unroll 4
  for(int t=0;t<CLEN;++t){
    int qs = __builtin_amdgcn_readfirstlane(qn2);
    const unsigned* cnp = corrH + qs*CORR_STRIDE;
    uint4 ca2 = *(const uint4*)(cnp);
    uint4 cb2 = *(const uint4*)(cnp+4);
    uint2 cc2 = *(const uint2*)(cnp+8);
    unsigned eanew = eaTab[(size_t)qa3*DV_ + dc];
    int t4 = (t+4 < CLEN) ? t+4 : CLEN-1;
    int qnew = qp[t4];
    int t6 = (t+6 < CLEN) ? t+6 : CLEN-1;
    int qanew = qap[t6];

    f16x2_t pe = h2(ea0);
    const f16x2_t ee = splat_l(pe), aa = splat_h(pe);
    #define UPDA(u, i) { \
      f16x2_t cp = h2(u); \
      f16x2_t al = pkfma16(-cp, ee, one2h); \
      f16x2_t be = cp*aa; \
      A2[i] = A2[i]*al; \
      B2[i] = pkfma16(al, B2[i], be); }
    UPDA(ca0.x, 0)  UPDA(ca0.y, 1)  UPDA(ca0.z, 2)  UPDA(ca0.w, 3)
    UPDA(cb0.x, 4)  UPDA(cb0.y, 5)  UPDA(cb0.z, 6)  UPDA(cb0.w, 7)
    UPDA(cc0.x, 8)  UPDA(cc0.y, 9)
    #undef UPDA

    ca0=ca1; cb0=cb1; cc0=cc1;
    ca1=ca2; cb1=cb2; cc1=cc2;
    qn2=qn3; qn3=qnew;
    ea0=ea1; ea1=ea2; ea2=eanew;
    qa3=qa4; qa4=qa5; qa5=qanew;
  }
  if(act){
    unsigned* base = ABu + ((size_t)(b*(CHK-1) + c)*MEM_)*DV_ + d;
    #pragma unroll
    for(int i=0;i<MEM_/2;++i){
      unsigned a01 = h2u(A2[i]);
      unsigned b01 = h2u(B2[i]);
      base[(size_t)(2*i)*DV_]   = (a01 & 0xffffu) | (b01 << 16);
      base[(size_t)(2*i+1)*DV_] = (a01 >> 16)     | (b01 & 0xffff0000u);
    }
  }
}

// K2: prefix — 7 composes (CHK=8).
__global__ __launch_bounds__(256) void k_prefix(const float* __restrict__ mv0,
    const unsigned* __restrict__ ABu, unsigned* __restrict__ Mv0p){
  int i = blockIdx.x*256 + threadIdx.x;
  if(i >= B_*(MEM_/2)*DV_) return;
  int d = i % DV_;
  int p = (i / DV_) % (MEM_/2);
  int b = i / (DV_*(MEM_/2));
  float MvE = mv0[(2*p)*DV_+d];
  float MvO = mv0[(2*p+1)*DV_+d];
  #pragma unroll
  for(int c=1;c<CHK;++c){
    unsigned vE = ABu[((size_t)(b*(CHK-1) + (c-1))*MEM_ + 2*p)*DV_ + d];
    unsigned vO = ABu[((size_t)(b*(CHK-1) + (c-1))*MEM_ + 2*p+1)*DV_ + d];
    MvE = fmaf((float)h2(vE)[0], MvE, (float)h2(vE)[1]);
    MvO = fmaf((float)h2(vO)[0], MvO, (float)h2(vO)[1]);
    Mv0p[((size_t)(b*CHK + c)*(MEM_/2) + p)*DV_ + d] = packh2(MvE, MvO);
  }
}

// K3: fused scan + MFMA (r9 structure, validated r10: WRITE 640KB, no spill).
// Scan all 64 steps into 64-row Xs, then fully-unrolled h=0,1 MFMA pass.
__global__ __launch_bounds__(256,8) void k_scan_mm(const int* __restrict__ qd,
    const int* __restrict__ qad,
    const unsigned* __restrict__ corrH,
    const unsigned* __restrict__ eaTab,
    const float* __restrict__ mv0,
    const unsigned* __restrict__ Mv0p,
    const unsigned short* __restrict__ WpFrag,
    const float* __restrict__ hq,
    const float* __restrict__ pwPad, const float* __restrict__ pb,
    const float* __restrict__ target,
    float* __restrict__ out, float2* __restrict__ partials){
  __shared__ unsigned short Xs[CLEN*XS_STRIDE];   // 29,696 B (64 rows)
  __shared__ float sred[2][2][16];
  __shared__ float sbce[4];

  const int blk = blockIdx.x;
  const int b = blk >> 3, c8 = blk & (CHK-1);
  const int d = threadIdx.x;
  const int dc = (d < DV_) ? d : DV_-1;
  const bool act = (d < DV_);
  const bool padw = (d < 224);
  const int* __restrict__ qp  = qd  + b*S_ + c8*CLEN;
  const int* __restrict__ qap = qad + b*S_ + c8*CLEN;

  const int wave = threadIdx.x >> 6;
  const int lane = threadIdx.x & 63;
  const int col  = lane & 15, quad = lane >> 4;
  const int rt   = wave & 1;
  const int nh   = wave >> 1;
  const int mbase = rt*16;

  f16x2_t Mv2[MEM_/2];
  if(c8 == 0){
    #pragma unroll
    for(int i=0;i<MEM_/2;++i)
      Mv2[i] = (f16x2_t){ (_Float16)mv0[(2*i)*DV_+dc], (_Float16)mv0[(2*i+1)*DV_+dc] };
  } else {
    const unsigned* base = Mv0p + ((size_t)(b*CHK + c8)*(MEM_/2))*DV_ + dc;
    #pragma unroll
    for(int i=0;i<MEM_/2;++i)
      Mv2[i] = h2(base[(size_t)i*DV_]);
  }

  // ---- single 64-step scan (r5 per-step code, primed once) ----
  unsigned ea0 = eaTab[(size_t)qap[0]*DV_ + dc];
  unsigned ea1 = eaTab[(size_t)qap[1]*DV_ + dc];
  unsigned ea2 = eaTab[(size_t)qap[2]*DV_ + dc];
  int qa3 = qap[3], qa4 = qap[4], qa5 = qap[5];
  int s0 = __builtin_amdgcn_readfirstlane(qp[0]);
  int s1 = __builtin_amdgcn_readfirstlane(qp[1]);
  const unsigned* c0p = corrH + s0*CORR_STRIDE;
  uint4 ca0 = *(const uint4*)(c0p); uint4 cb0 = *(const uint4*)(c0p+4); uint2 cc0 = *(const uint2*)(c0p+8);
  const unsigned* c1p = corrH + s1*CORR_STRIDE;
  uint4 ca1 = *(const uint4*)(c1p); uint4 cb1 = *(const uint4*)(c1p+4); uint2 cc1 = *(const uint2*)(c1p+8);
  int qn2 = qp[2], qn3 = qp[3];

  #pragma unroll 4
  for(int t=0;t<CLEN;++t){
    int qs = __builtin_amdgcn_readfirstlane(qn2);
    const unsigned* cnp = corrH + qs*CORR_STRIDE;
    uint4 ca2 = *(const uint4*)(cnp);
    uint4 cb2 = *(const uint4*)(cnp+4);
    uint2 cc2 = *(const uint2*)(cnp+8);
    unsigned eanew = eaTab[(size_t)qa3*DV_ + dc];
    int t4 = (t+4 < CLEN) ? t+4 : CLEN-1;
    int qnew = qp[t4];
    int t6 = (t+6 < CLEN) ? t+6 : CLEN-1;
    int qanew = qap[t6];

    f16x2_t pe = h2(ea0);
    const f16x2_t ee = splat_l(pe), aa = splat_h(pe);
    float rd0 = 0.f, rd1 = 0.f;
    #define UPD2(u, i, acc) { \
      f16x2_t cp = h2(u); \
      acc = __builtin_amdgcn_fdot2(cp, Mv2[i], acc, false); \
      f16x2_t tt = pkfma16(-Mv2[i], ee, aa); \
      Mv2[i] = pkfma16(cp, tt, Mv2[i]); }
    UPD2(ca0.x, 0, rd0)  UPD2(ca0.y, 1, rd1)  UPD2(ca0.z, 2, rd0)  UPD2(ca0.w, 3, rd1)
    UPD2(cb0.x, 4, rd0)  UPD2(cb0.y, 5, rd1)  UPD2(cb0.z, 6, rd0)  UPD2(cb0.w, 7, rd1)
    UPD2(cc0.x, 8, rd0)  UPD2(cc0.y, 9, rd1)
    #undef UPD2

    if(padw) Xs[t*XS_STRIDE + d] = act ? f2bf(rd0+rd1) : (unsigned short)0;

    ca0=ca1; cb0=cb1; cc0=cc1;
    ca1=ca2; cb1=cb2; cc1=cc2;
    qn2=qn3; qn3=qnew;
    ea0=ea1; ea1=ea2; ea2=eanew;
    qa3=qa4; qa4=qa5; qa5=qanew;
  }
  __syncthreads();
  // ---- scan state dead here; MFMA phases follow ----

  float bceAcc = 0.f, cntAcc = 0.f;
  const float pbv = pb[0];

  #pragma unroll
  for(int h=0;h<2;++h){              // compile-time h (fully unrolled)
    const int g0 = h*HLEN;

    int qpre[4];
    #pragma unroll
    for(int reg=0;reg<4;++reg) qpre[reg] = qp[g0 + mbase + quad*4 + reg];
    float hqv[4][2];
    #pragma unroll
    for(int reg=0;reg<4;++reg)
      #pragma unroll
      for(int j=0;j<2;++j)
        hqv[reg][j] = hq[qpre[reg]*64 + (nh*2+j)*16 + col];

    f32x4_t acc[2];
    acc[0] = (f32x4_t){0.f,0.f,0.f,0.f};
    acc[1] = (f32x4_t){0.f,0.f,0.f,0.f};
    #pragma unroll
    for(int ks=0;ks<NKS;++ks){
      bf16x8_t a = *reinterpret_cast<const bf16x8_t*>(Xs + (g0 + mbase + col)*XS_STRIDE + quad*8 + ks*32);
      #pragma unroll
      for(int j=0;j<2;++j){
        int nt = nh*2 + j;
        bf16x8_t bfr = *reinterpret_cast<const bf16x8_t*>(WpFrag + ((size_t)(ks*4+nt)*64 + lane)*8);
        acc[j] = __builtin_amdgcn_mfma_f32_16x16x32_bf16(a, bfr, acc[j], 0, 0, 0);
      }
    }

    float part[4];
    #pragma unroll
    for(int reg=0;reg<4;++reg){
      float s = 0.f;
      #pragma unroll
      for(int j=0;j<2;++j){
        int n = (nh*2+j)*16 + col;
        float hh = acc[j][reg] + hqv[reg][j];
        s = fmaf(pwPad[n], ftanh(hh), s);
      }
      part[reg] = s;
    }
    #pragma unroll
    for(int off=1; off<16; off<<=1){
      #pragma unroll
      for(int reg=0;reg<4;++reg) part[reg] += __shfl_xor(part[reg], off, 64);
    }
    if(col == 0){
      #pragma unroll
      for(int reg=0;reg<4;++reg) sred[rt][nh][quad*4+reg] = part[reg];
    }
    __syncthreads();

    if(nh == 0 && col == 0){
      #pragma unroll
      for(int reg=0;reg<4;++reg){
        int idx = quad*4 + reg;
        int mloc = mbase + idx;
        int row = b*S_ + c8*CLEN + g0 + mloc;
        float logit = sred[rt][0][idx] + sred[rt][1][idx] + pbv;
        out[1+row] = fsigm(logit);
        float t = target[row];
        if(t >= 0.f){
          cntAcc += 1.f;
          bceAcc += fmaxf(logit,0.f) - logit*t + log1pf(__expf(-fabsf(logit)));
        }
      }
    }
    __syncthreads();                 // sred safe for next half's writers
  }

  bceAcc += __shfl_xor(bceAcc, 16, 64); cntAcc += __shfl_xor(cntAcc, 16, 64);
  bceAcc += __shfl_xor(bceAcc, 32, 64); cntAcc += __shfl_xor(cntAcc, 32, 64);
  if(lane == 0 && nh == 0){ sbce[wave] = bceAcc; sbce[2+wave] = cntAcc; }
  __syncthreads();
  if(threadIdx.x == 0)
    partials[blk] = make_float2(sbce[0]+sbce[1], sbce[2]+sbce[3]);
}

// K4: reduce per-block partials -> loss
__global__ __launch_bounds__(256) void k_fin(const float2* __restrict__ partials,
                                             float* __restrict__ out){
  float bce = 0.f, cnt = 0.f;
  for(int i=threadIdx.x; i<MM_BLOCKS; i+=256){
    float2 p = partials[i];
    bce += p.x; cnt += p.y;
  }
  #pragma unroll
  for(int off=32; off>0; off>>=1){
    bce += __shfl_down(bce, off, 64);
    cnt += __shfl_down(cnt, off, 64);
  }
  __shared__ float sb[4], sc[4];
  int w = threadIdx.x >> 6;
  if((threadIdx.x & 63) == 0){ sb[w] = bce; sc[w] = cnt; }
  __syncthreads();
  if(threadIdx.x == 0){
    float Bt = sb[0]+sb[1]+sb[2]+sb[3];
    float Ct = sc[0]+sc[1]+sc[2]+sc[3];
    out[0] = Bt / fmaxf(Ct, 1.f);
  }
}

extern "C" void kernel_launch(void* const* d_in, const int* in_sizes, int n_in,
                              void* d_out, int out_size, void* d_ws, size_t ws_size,
                              hipStream_t stream){
  const int*   qd     = (const int*)d_in[0];
  const int*   qad    = (const int*)d_in[1];
  const float* target = (const float*)d_in[2];
  const float* qw     = (const float*)d_in[3];
  const float* qaw    = (const float*)d_in[4];
  const float* mk     = (const float*)d_in[5];
  const float* mv0    = (const float*)d_in[6];
  const float* ew     = (const float*)d_in[7];
  const float* eb     = (const float*)d_in[8];
  const float* aw     = (const float*)d_in[9];
  const float* ab     = (const float*)d_in[10];
  const float* rw     = (const float*)d_in[11];
  const float* rb     = (const float*)d_in[12];
  const float* pw     = (const float*)d_in[13];
  const float* pb     = (const float*)d_in[14];
  float* out = (float*)d_out;

  char* ws = (char*)d_ws;
  size_t off = 0;
  float2* partials = (float2*)(ws + off);            off += (size_t)MM_BLOCKS*8;
  unsigned* corrH = (unsigned*)(ws + off);           off += (((size_t)(NQ_+1)*CORR_STRIDE*4 + 255)/256)*256;
  unsigned* eaTab = (unsigned*)(ws + off);           off += (((size_t)(2*NQ_+1)*DV_*4 + 255)/256)*256;
  unsigned* ABu   = (unsigned*)(ws + off);           off += (size_t)SCANA_BLOCKS*MEM_*DV_*4;
  unsigned* Mv0p  = (unsigned*)(ws + off);           off += (size_t)MM_BLOCKS*(MEM_/2)*DV_*4;
  unsigned short* WpFrag = (unsigned short*)(ws + off); off += ((size_t)NKS*4*64*8*2 + 255)/256*256;
  float* pwPad    = (float*)(ws + off);              off += 256;
  float* hq       = (float*)(ws + off);              off += (size_t)(NQ_+1)*64*4;

  k_prep1<<<dim3(PREP_BLOCKS), dim3(256), 0, stream>>>(qaw, ew, eb, aw, ab, eaTab,
                                                       qw, mk, corrH,
                                                       rw, rb, pw, WpFrag, pwPad, hq);
  k_scanA<<<dim3(SCANA_BLOCKS), dim3(256), 0, stream>>>(qd, qad, corrH, eaTab, ABu);
  k_prefix<<<dim3((B_*(MEM_/2)*DV_+255)/256), dim3(256), 0, stream>>>(mv0, ABu, Mv0p);
  k_scan_mm<<<dim3(MM_BLOCKS), dim3(256), 0, stream>>>(qd, qad, corrH, eaTab,
                                                       mv0, Mv0p, WpFrag, hq, pwPad, pb, target, out, partials);
  k_fin<<<dim3(1), dim3(256), 0, stream>>>(partials, out);
}

// Round 13
// 219.343 us; speedup vs baseline: 1.0535x; 1.0535x over previous
//
#include <hip/hip_runtime.h>
#include <math.h>

#define B_   256
#define S_   512
#define NQ_  1000
#define MEM_ 20
#define DK_  50
#define DV_  200
#define FC_  50
#define RPB  2              // r4: doubles TLP on prep1's latency-exposed GEMM loop
#define CHK  8              // r7: 16->8 — halves ABu/Mv0p/prefix glue traffic
#define CLEN (S_/CHK)       // 64 steps per chunk
#define HLEN 32             // MFMA half-chunk (rows per MFMA phase)
#define NKS  7              // K-steps for MFMA (K = 224 = 200 reads + 24 zero)
#define XS_STRIDE 232       // LDS row stride in bf16 (224 + 8 pad)
#define CORR_STRIDE 12      // uints per corr row (10 used + 2 pad -> 48B)
#define NB_EA    ((2*NQ_+1+RPB-1)/RPB)   // 1001
#define NB_CORR  4
#define NB_WPACK 7
#define NB_HQ    251
#define PREP_BLOCKS (NB_EA+NB_CORR+NB_WPACK+NB_HQ)  // 1263
#define MM_BLOCKS (B_*CHK)        // 2048
#define SCANA_BLOCKS (B_*(CHK-1)) // 1792

typedef __attribute__((ext_vector_type(8))) short bf16x8_t;
typedef __attribute__((ext_vector_type(4))) float f32x4_t;
typedef __attribute__((ext_vector_type(2))) _Float16 f16x2_t;

static __device__ __forceinline__ f16x2_t h2(unsigned u){ return __builtin_bit_cast(f16x2_t, u); }
static __device__ __forceinline__ unsigned h2u(f16x2_t v){ return __builtin_bit_cast(unsigned, v); }
static __device__ __forceinline__ unsigned packh2(float x, float y){
  unsigned short bx = __builtin_bit_cast(unsigned short, (_Float16)x);
  unsigned short by = __builtin_bit_cast(unsigned short, (_Float16)y);
  return (unsigned)bx | ((unsigned)by << 16);
}
static __device__ __forceinline__ f16x2_t pkfma16(f16x2_t a, f16x2_t b, f16x2_t c){
  return __builtin_elementwise_fma(a, b, c);     // -> v_pk_fma_f16 (full rate)
}
static __device__ __forceinline__ f16x2_t splat_l(f16x2_t p){ return __builtin_shufflevector(p, p, 0, 0); }
static __device__ __forceinline__ f16x2_t splat_h(f16x2_t p){ return __builtin_shufflevector(p, p, 1, 1); }

static __device__ __forceinline__ unsigned short f2bf(float f){
  unsigned u = __float_as_uint(f);
  unsigned r = u + 0x7fffu + ((u >> 16) & 1u);   // round-to-nearest-even
  return (unsigned short)(r >> 16);
}
static __device__ __forceinline__ float ftanh(float x){
  float e = __expf(2.f*x);
  return 1.f - 2.f*__builtin_amdgcn_rcpf(e+1.f);
}
static __device__ __forceinline__ float fsigm(float x){
  return __builtin_amdgcn_rcpf(1.f+__expf(-x));
}

// r12 scan addressing: lane l holds qp[l]/qap[l]; in-loop row indices via
// v_readlane with the uniform step index — zero memory ops for addressing.
#define RL(v, i) __builtin_amdgcn_readlane(v, i)
#define GEA(DST, IX) { int r_ = RL(vqap, IX); \
  DST = *(const unsigned*)((const char*)eaTab + (size_t)r_*(DV_*4u) + ((unsigned)dc*4u)); }
#define GCORR(CA,CB,CC, IX) { int r_ = RL(vqp, IX); \
  const unsigned* p_ = corrH + r_*CORR_STRIDE; \
  CA = *(const uint4*)(p_); CB = *(const uint4*)(p_+4); CC = *(const uint2*)(p_+8); }

// K0: prep — [0,1001): eaTab; [1001,1005): corrH; [1005,1012): WpFrag+pwPad;
// [1012,1263): hq.  Reverted to the r10/216.2 version (r12 MFMA variant
// regressed: its 44.5KB LDS footprint applied to ALL merged-grid blocks,
// throttling the tail branches' occupancy 8->3 blocks/CU).
__global__ __launch_bounds__(256) void k_prep1(
    const float* __restrict__ qaw,
    const float* __restrict__ ew, const float* __restrict__ eb,
    const float* __restrict__ aw, const float* __restrict__ ab,
    unsigned* __restrict__ eaTab,
    const float* __restrict__ qw, const float* __restrict__ mk,
    unsigned* __restrict__ corrH,
    const float* __restrict__ rw, const float* __restrict__ rb,
    const float* __restrict__ pw,
    unsigned short* __restrict__ WpFrag, float* __restrict__ pwPad,
    float* __restrict__ hq){
  __shared__ float qa[RPB*DV_];
  int blk = blockIdx.x;
  if(blk < NB_EA){
    int row0 = blk*RPB;
    for(int i=threadIdx.x; i<RPB*DV_; i+=256){
      int r = i/DV_, cc = i - r*DV_;
      int row = row0 + r;
      qa[i] = (row <= 2*NQ_) ? qaw[row*DV_+cc] : 0.f;
    }
    __syncthreads();
    int d = threadIdx.x;
    if(d >= DV_) return;
    float accE[RPB], accA[RPB];
    #pragma unroll
    for(int r=0;r<RPB;++r){ accE[r] = eb[d]; accA[r] = ab[d]; }
    float we0 = ew[d], wa0 = aw[d];
    for(int j=0;j<DV_;++j){
      int jn = (j+1 < DV_) ? j+1 : j;
      float we1 = ew[jn*DV_+d];
      float wa1 = aw[jn*DV_+d];
      #pragma unroll
      for(int r=0;r<RPB;++r){
        float x = qa[r*DV_+j];
        accE[r] = fmaf(x, we0, accE[r]);
        accA[r] = fmaf(x, wa0, accA[r]);
      }
      we0 = we1; wa0 = wa1;
    }
    #pragma unroll
    for(int r=0;r<RPB;++r){
      int row = row0 + r;
      if(row <= 2*NQ_){
        unsigned he = (unsigned)__builtin_bit_cast(unsigned short, (_Float16)fsigm(accE[r]));
        unsigned ha = (unsigned)__builtin_bit_cast(unsigned short, (_Float16)ftanh(accA[r]));
        eaTab[(size_t)row*DV_+d] = he | (ha << 16);
      }
    }
  } else if(blk < NB_EA+NB_CORR){
    int q = (blk-NB_EA)*256 + threadIdx.x;
    if(q > NQ_) return;
    float qv[DK_];
    #pragma unroll
    for(int j=0;j<DK_;++j) qv[j] = qw[q*DK_+j];
    float s[MEM_]; float mx = -1e30f;
    #pragma unroll
    for(int m=0;m<MEM_;++m){
      float acc = 0.f;
      #pragma unroll
      for(int j=0;j<DK_;++j) acc = fmaf(qv[j], mk[m*DK_+j], acc);
      s[m] = acc; mx = fmaxf(mx, acc);
    }
    float sum = 0.f;
    #pragma unroll
    for(int m=0;m<MEM_;++m){ s[m] = __expf(s[m]-mx); sum += s[m]; }
    float inv = __builtin_amdgcn_rcpf(sum);
    #pragma unroll
    for(int i=0;i<MEM_/2;++i)
      corrH[q*CORR_STRIDE+i] = packh2(s[2*i]*inv, s[2*i+1]*inv);
  } else if(blk < NB_EA+NB_CORR+NB_WPACK){
    int ks = blk - (NB_EA+NB_CORR);
    int nt = threadIdx.x >> 6;
    int lane = threadIdx.x & 63;
    int quad = lane >> 4, col = lane & 15;
    int n = nt*16 + col;
    unsigned short tmp[8];
    #pragma unroll
    for(int j=0;j<8;++j){
      int k = ks*32 + quad*8 + j;
      tmp[j] = (k < DV_ && n < FC_) ? f2bf(rw[k*FC_+n]) : (unsigned short)0;
    }
    uint4* dst = reinterpret_cast<uint4*>(WpFrag + ((size_t)(ks*4+nt)*64 + lane)*8);
    *dst = *reinterpret_cast<const uint4*>(tmp);
    if(ks == 0 && threadIdx.x < 64)
      pwPad[threadIdx.x] = (threadIdx.x < FC_) ? pw[threadIdx.x] : 0.f;
  } else {
    int idx = (blk-(NB_EA+NB_CORR+NB_WPACK))*256 + threadIdx.x;
    int q = idx >> 6, n = idx & 63;
    if(q > NQ_) return;
    float v = 0.f;
    if(n < FC_){
      float acc = rb[n];
      #pragma unroll
      for(int j=0;j<DK_;++j)
        acc = fmaf(qw[q*DK_+j], rw[(DV_+j)*FC_+n], acc);
      v = acc;
    }
    hq[q*64+n] = v;
  }
}

// K1: phase 1 — per-chunk affine (A,B) over 64 steps. r12: ea gather depth 8
// (800cy cover vs L3-hit ~600-900cy — the one cover level never tested; r0/r1
// tried 3/4, both below threshold), period-8 modulo schedule (zero rotation),
// readlane-resident indices (no in-loop index loads).
__global__ __launch_bounds__(256,8) void k_scanA(const int* __restrict__ qd,
    const int* __restrict__ qad,
    const unsigned* __restrict__ corrH,
    const unsigned* __restrict__ eaTab,
    unsigned* __restrict__ ABu){
  const int blk = blockIdx.x;
  const int b = blk / (CHK-1), c = blk % (CHK-1);
  const int d = threadIdx.x;
  const int dc = (d < DV_) ? d : DV_-1;
  const bool act = (d < DV_);
  const int lane = d & 63;
  const int* __restrict__ qp  = qd  + b*S_ + c*CLEN;
  const int* __restrict__ qap = qad + b*S_ + c*CLEN;

  int vqp  = qp[lane];      // lane l holds step-l index (replicated per wave)
  int vqap = qap[lane];

  const f16x2_t one2h = {(_Float16)1.f, (_Float16)1.f};
  f16x2_t A2[MEM_/2], B2[MEM_/2];
  #pragma unroll
  for(int i=0;i<MEM_/2;++i){ A2[i] = one2h; B2[i] = (f16x2_t){(_Float16)0.f,(_Float16)0.f}; }

  unsigned ea0,ea1,ea2,ea3,ea4,ea5,ea6,ea7;
  GEA(ea0,0) GEA(ea1,1) GEA(ea2,2) GEA(ea3,3)
  GEA(ea4,4) GEA(ea5,5) GEA(ea6,6) GEA(ea7,7)
  uint4 ca0,cb0,ca1,cb1; uint2 cc0,cc1;
  GCORR(ca0,cb0,cc0, 0)
  GCORR(ca1,cb1,cc1, 1)

  #define STEPA(EA, CA, CB, CC) { \
    f16x2_t pe = h2(EA); \
    const f16x2_t ee = splat_l(pe), aa = splat_h(pe); \
    UPDA(CA.x, 0)  UPDA(CA.y, 1)  UPDA(CA.z, 2)  UPDA(CA.w, 3) \
    UPDA(CB.x, 4)  UPDA(CB.y, 5)  UPDA(CB.z, 6)  UPDA(CB.w, 7) \
    UPDA(CC.x, 8)  UPDA(CC.y, 9) }
  #define UPDA(u, i) { \
    f16x2_t cp = h2(u); \
    f16x2_t al = pkfma16(-cp, ee, one2h); \
    f16x2_t be = cp*aa; \
    A2[i] = A2[i]*al; \
    B2[i] = pkfma16(al, B2[i], be); }
  #define SLOTA(K, EA, CA, CB, CC) { \
    STEPA(EA, CA, CB, CC) \
    { int ix = t+(K)+2; ix = (ix<CLEN)?ix:CLEN-1; GCORR(CA,CB,CC, ix) } \
    { int ix = t+(K)+8; ix = (ix<CLEN)?ix:CLEN-1; GEA(EA, ix) } }

  #pragma unroll 1
  for(int t=0;t<CLEN;t+=8){
    SLOTA(0, ea0, ca0,cb0,cc0)
    SLOTA(1, ea1, ca1,cb1,cc1)
    SLOTA(2, ea2, ca0,cb0,cc0)
    SLOTA(3, ea3, ca1,cb1,cc1)
    SLOTA(4, ea4, ca0,cb0,cc0)
    SLOTA(5, ea5, ca1,cb1,cc1)
    SLOTA(6, ea6, ca0,cb0,cc0)
    SLOTA(7, ea7, ca1,cb1,cc1)
  }
  #undef SLOTA
  #undef UPDA
  #undef STEPA

  if(act){
    unsigned* base = ABu + ((size_t)(b*(CHK-1) + c)*MEM_)*DV_ + d;
    #pragma unroll
    for(int i=0;i<MEM_/2;++i){
      unsigned a01 = h2u(A2[i]);
      unsigned b01 = h2u(B2[i]);
      base[(size_t)(2*i)*DV_]   = (a01 & 0xffffu) | (b01 << 16);
      base[(size_t)(2*i+1)*DV_] = (a01 >> 16)     | (b01 & 0xffff0000u);
    }
  }
}

// K2: prefix — 7 composes (CHK=8).
__global__ __launch_bounds__(256) void k_prefix(const float* __restrict__ mv0,
    const unsigned* __restrict__ ABu, unsigned* __restrict__ Mv0p){
  int i = blockIdx.x*256 + threadIdx.x;
  if(i >= B_*(MEM_/2)*DV_) return;
  int d = i % DV_;
  int p = (i / DV_) % (MEM_/2);
  int b = i / (DV_*(MEM_/2));
  float MvE = mv0[(2*p)*DV_+d];
  float MvO = mv0[(2*p+1)*DV_+d];
  #pragma unroll
  for(int c=1;c<CHK;++c){
    unsigned vE = ABu[((size_t)(b*(CHK-1) + (c-1))*MEM_ + 2*p)*DV_ + d];
    unsigned vO = ABu[((size_t)(b*(CHK-1) + (c-1))*MEM_ + 2*p+1)*DV_ + d];
    MvE = fmaf((float)h2(vE)[0], MvE, (float)h2(vE)[1]);
    MvO = fmaf((float)h2(vO)[0], MvO, (float)h2(vO)[1]);
    Mv0p[((size_t)(b*CHK + c)*(MEM_/2) + p)*DV_ + d] = packh2(MvE, MvO);
  }
}

// K3: fused scan + MFMA (r9 structure; r10 validated no-spill). r12: same
// depth-8 ea pipeline + readlane indices as k_scanA. Scan all 64 steps into
// 64-row Xs, then fully-unrolled h=0,1 MFMA pass.
__global__ __launch_bounds__(256,8) void k_scan_mm(const int* __restrict__ qd,
    const int* __restrict__ qad,
    const unsigned* __restrict__ corrH,
    const unsigned* __restrict__ eaTab,
    const float* __restrict__ mv0,
    const unsigned* __restrict__ Mv0p,
    const unsigned short* __restrict__ WpFrag,
    const float* __restrict__ hq,
    const float* __restrict__ pwPad, const float* __restrict__ pb,
    const float* __restrict__ target,
    float* __restrict__ out, float2* __restrict__ partials){
  __shared__ unsigned short Xs[CLEN*XS_STRIDE];   // 29,696 B (64 rows)
  __shared__ float sred[2][2][16];
  __shared__ float sbce[4];

  const int blk = blockIdx.x;
  const int b = blk >> 3, c8 = blk & (CHK-1);
  const int d = threadIdx.x;
  const int dc = (d < DV_) ? d : DV_-1;
  const bool act = (d < DV_);
  const bool padw = (d < 224);
  const int* __restrict__ qp  = qd  + b*S_ + c8*CLEN;
  const int* __restrict__ qap = qad + b*S_ + c8*CLEN;

  const int wave = threadIdx.x >> 6;
  const int lane = threadIdx.x & 63;
  const int col  = lane & 15, quad = lane >> 4;
  const int rt   = wave & 1;
  const int nh   = wave >> 1;
  const int mbase = rt*16;

  int vqp  = qp[lane];
  int vqap = qap[lane];

  f16x2_t Mv2[MEM_/2];
  if(c8 == 0){
    #pragma unroll
    for(int i=0;i<MEM_/2;++i)
      Mv2[i] = (f16x2_t){ (_Float16)mv0[(2*i)*DV_+dc], (_Float16)mv0[(2*i+1)*DV_+dc] };
  } else {
    const unsigned* base = Mv0p + ((size_t)(b*CHK + c8)*(MEM_/2))*DV_ + dc;
    #pragma unroll
    for(int i=0;i<MEM_/2;++i)
      Mv2[i] = h2(base[(size_t)i*DV_]);
  }

  unsigned ea0,ea1,ea2,ea3,ea4,ea5,ea6,ea7;
  GEA(ea0,0) GEA(ea1,1) GEA(ea2,2) GEA(ea3,3)
  GEA(ea4,4) GEA(ea5,5) GEA(ea6,6) GEA(ea7,7)
  uint4 ca0,cb0,ca1,cb1; uint2 cc0,cc1;
  GCORR(ca0,cb0,cc0, 0)
  GCORR(ca1,cb1,cc1, 1)

  #define UPD2(u, i, acc) { \
    f16x2_t cp = h2(u); \
    acc = __builtin_amdgcn_fdot2(cp, Mv2[i], acc, false); \
    f16x2_t tt = pkfma16(-Mv2[i], ee, aa); \
    Mv2[i] = pkfma16(cp, tt, Mv2[i]); }
  #define STEPM(T_, EA, CA, CB, CC) { \
    f16x2_t pe = h2(EA); \
    const f16x2_t ee = splat_l(pe), aa = splat_h(pe); \
    float rd0 = 0.f, rd1 = 0.f; \
    UPD2(CA.x, 0, rd0)  UPD2(CA.y, 1, rd1)  UPD2(CA.z, 2, rd0)  UPD2(CA.w, 3, rd1) \
    UPD2(CB.x, 4, rd0)  UPD2(CB.y, 5, rd1)  UPD2(CB.z, 6, rd0)  UPD2(CB.w, 7, rd1) \
    UPD2(CC.x, 8, rd0)  UPD2(CC.y, 9, rd1) \
    if(padw) Xs[(T_)*XS_STRIDE + d] = act ? f2bf(rd0+rd1) : (unsigned short)0; }
  #define SLOTM(K, EA, CA, CB, CC) { \
    STEPM(t+(K), EA, CA, CB, CC) \
    { int ix = t+(K)+2; ix = (ix<CLEN)?ix:CLEN-1; GCORR(CA,CB,CC, ix) } \
    { int ix = t+(K)+8; ix = (ix<CLEN)?ix:CLEN-1; GEA(EA, ix) } }

  #pragma unroll 1
  for(int t=0;t<CLEN;t+=8){
    SLOTM(0, ea0, ca0,cb0,cc0)
    SLOTM(1, ea1, ca1,cb1,cc1)
    SLOTM(2, ea2, ca0,cb0,cc0)
    SLOTM(3, ea3, ca1,cb1,cc1)
    SLOTM(4, ea4, ca0,cb0,cc0)
    SLOTM(5, ea5, ca1,cb1,cc1)
    SLOTM(6, ea6, ca0,cb0,cc0)
    SLOTM(7, ea7, ca1,cb1,cc1)
  }
  #undef SLOTM
  #undef STEPM
  #undef UPD2
  __syncthreads();
  // ---- scan state dead here; MFMA phases follow ----

  float bceAcc = 0.f, cntAcc = 0.f;
  const float pbv = pb[0];

  #pragma unroll
  for(int h=0;h<2;++h){              // compile-time h (fully unrolled)
    const int g0 = h*HLEN;

    int qpre[4];
    #pragma unroll
    for(int reg=0;reg<4;++reg) qpre[reg] = qp[g0 + mbase + quad*4 + reg];
    float hqv[4][2];
    #pragma unroll
    for(int reg=0;reg<4;++reg)
      #pragma unroll
      for(int j=0;j<2;++j)
        hqv[reg][j] = hq[qpre[reg]*64 + (nh*2+j)*16 + col];

    f32x4_t acc[2];
    acc[0] = (f32x4_t){0.f,0.f,0.f,0.f};
    acc[1] = (f32x4_t){0.f,0.f,0.f,0.f};
    #pragma unroll
    for(int ks=0;ks<NKS;++ks){
      bf16x8_t a = *reinterpret_cast<const bf16x8_t*>(Xs + (g0 + mbase + col)*XS_STRIDE + quad*8 + ks*32);
      #pragma unroll
      for(int j=0;j<2;++j){
        int nt = nh*2 + j;
        bf16x8_t bfr = *reinterpret_cast<const bf16x8_t*>(WpFrag + ((size_t)(ks*4+nt)*64 + lane)*8);
        acc[j] = __builtin_amdgcn_mfma_f32_16x16x32_bf16(a, bfr, acc[j], 0, 0, 0);
      }
    }

    float part[4];
    #pragma unroll
    for(int reg=0;reg<4;++reg){
      float s = 0.f;
      #pragma unroll
      for(int j=0;j<2;++j){
        int n = (nh*2+j)*16 + col;
        float hh = acc[j][reg] + hqv[reg][j];
        s = fmaf(pwPad[n], ftanh(hh), s);
      }
      part[reg] = s;
    }
    #pragma unroll
    for(int off=1; off<16; off<<=1){
      #pragma unroll
      for(int reg=0;reg<4;++reg) part[reg] += __shfl_xor(part[reg], off, 64);
    }
    if(col == 0){
      #pragma unroll
      for(int reg=0;reg<4;++reg) sred[rt][nh][quad*4+reg] = part[reg];
    }
    __syncthreads();

    if(nh == 0 && col == 0){
      #pragma unroll
      for(int reg=0;reg<4;++reg){
        int idx = quad*4 + reg;
        int mloc = mbase + idx;
        int row = b*S_ + c8*CLEN + g0 + mloc;
        float logit = sred[rt][0][idx] + sred[rt][1][idx] + pbv;
        out[1+row] = fsigm(logit);
        float t = target[row];
        if(t >= 0.f){
          cntAcc += 1.f;
          bceAcc += fmaxf(logit,0.f) - logit*t + log1pf(__expf(-fabsf(logit)));
        }
      }
    }
    __syncthreads();                 // sred safe for next half's writers
  }

  bceAcc += __shfl_xor(bceAcc, 16, 64); cntAcc += __shfl_xor(cntAcc, 16, 64);
  bceAcc += __shfl_xor(bceAcc, 32, 64); cntAcc += __shfl_xor(cntAcc, 32, 64);
  if(lane == 0 && nh == 0){ sbce[wave] = bceAcc; sbce[2+wave] = cntAcc; }
  __syncthreads();
  if(threadIdx.x == 0)
    partials[blk] = make_float2(sbce[0]+sbce[1], sbce[2]+sbce[3]);
}

// K4: reduce per-block partials -> loss
__global__ __launch_bounds__(256) void k_fin(const float2* __restrict__ partials,
                                             float* __restrict__ out){
  float bce = 0.f, cnt = 0.f;
  for(int i=threadIdx.x; i<MM_BLOCKS; i+=256){
    float2 p = partials[i];
    bce += p.x; cnt += p.y;
  }
  #pragma unroll
  for(int off=32; off>0; off>>=1){
    bce += __shfl_down(bce, off, 64);
    cnt += __shfl_down(cnt, off, 64);
  }
  __shared__ float sb[4], sc[4];
  int w = threadIdx.x >> 6;
  if((threadIdx.x & 63) == 0){ sb[w] = bce; sc[w] = cnt; }
  __syncthreads();
  if(threadIdx.x == 0){
    float Bt = sb[0]+sb[1]+sb[2]+sb[3];
    float Ct = sc[0]+sc[1]+sc[2]+sc[3];
    out[0] = Bt / fmaxf(Ct, 1.f);
  }
}

extern "C" void kernel_launch(void* const* d_in, const int* in_sizes, int n_in,
                              void* d_out, int out_size, void* d_ws, size_t ws_size,
                              hipStream_t stream){
  const int*   qd     = (const int*)d_in[0];
  const int*   qad    = (const int*)d_in[1];
  const float* target = (const float*)d_in[2];
  const float* qw     = (const float*)d_in[3];
  const float* qaw    = (const float*)d_in[4];
  const float* mk     = (const float*)d_in[5];
  const float* mv0    = (const float*)d_in[6];
  const float* ew     = (const float*)d_in[7];
  const float* eb     = (const float*)d_in[8];
  const float* aw     = (const float*)d_in[9];
  const float* ab     = (const float*)d_in[10];
  const float* rw     = (const float*)d_in[11];
  const float* rb     = (const float*)d_in[12];
  const float* pw     = (const float*)d_in[13];
  const float* pb     = (const float*)d_in[14];
  float* out = (float*)d_out;

  char* ws = (char*)d_ws;
  size_t off = 0;
  float2* partials = (float2*)(ws + off);            off += (size_t)MM_BLOCKS*8;
  unsigned* corrH = (unsigned*)(ws + off);           off += (((size_t)(NQ_+1)*CORR_STRIDE*4 + 255)/256)*256;
  unsigned* eaTab = (unsigned*)(ws + off);           off += (((size_t)(2*NQ_+1)*DV_*4 + 255)/256)*256;
  unsigned* ABu   = (unsigned*)(ws + off);           off += (size_t)SCANA_BLOCKS*MEM_*DV_*4;
  unsigned* Mv0p  = (unsigned*)(ws + off);           off += (size_t)MM_BLOCKS*(MEM_/2)*DV_*4;
  unsigned short* WpFrag = (unsigned short*)(ws + off); off += ((size_t)NKS*4*64*8*2 + 255)/256*256;
  float* pwPad    = (float*)(ws + off);              off += 256;
  float* hq       = (float*)(ws + off);              off += (size_t)(NQ_+1)*64*4;

  k_prep1<<<dim3(PREP_BLOCKS), dim3(256), 0, stream>>>(qaw, ew, eb, aw, ab, eaTab,
                                                       qw, mk, corrH,
                                                       rw, rb, pw, WpFrag, pwPad, hq);
  k_scanA<<<dim3(SCANA_BLOCKS), dim3(256), 0, stream>>>(qd, qad, corrH, eaTab, ABu);
  k_prefix<<<dim3((B_*(MEM_/2)*DV_+255)/256), dim3(256), 0, stream>>>(mv0, ABu, Mv0p);
  k_scan_mm<<<dim3(MM_BLOCKS), dim3(256), 0, stream>>>(qd, qad, corrH, eaTab,
                                                       mv0, Mv0p, WpFrag, hq, pwPad, pb, target, out, partials);
  k_fin<<<dim3(1), dim3(256), 0, stream>>>(partials, out);
}

// Round 14
// 215.095 us; speedup vs baseline: 1.0743x; 1.0198x over previous
//
#include <hip/hip_runtime.h>
#include <math.h>

#define B_   256
#define S_   512
#define NQ_  1000
#define MEM_ 20
#define DK_  50
#define DV_  200
#define FC_  50
#define RPB  2              // r4: doubles TLP on prep1's latency-exposed GEMM loop
#define CHK  8              // r7: 16->8 — halves ABu/Mv0p/prefix glue traffic
#define CLEN (S_/CHK)       // 64 steps per chunk
#define HLEN 32             // MFMA half-chunk (rows per MFMA phase)
#define NKS  7              // K-steps for MFMA (K = 224 = 200 reads + 24 zero)
#define XS_STRIDE 232       // LDS row stride in bf16 (224 + 8 pad)
#define CORR_STRIDE 12      // uints per corr row (10 used + 2 pad -> 48B)
#define NB_EA    ((2*NQ_+1+RPB-1)/RPB)   // 1001
#define NB_CORR  4
#define NB_WPACK 7
#define NB_HQ    251
#define PREP_BLOCKS (NB_EA+NB_CORR+NB_WPACK+NB_HQ)  // 1263
#define MM_BLOCKS (B_*CHK)        // 2048
#define SCANA_BLOCKS (B_*(CHK-1)) // 1792

typedef __attribute__((ext_vector_type(8))) short bf16x8_t;
typedef __attribute__((ext_vector_type(4))) float f32x4_t;
typedef __attribute__((ext_vector_type(2))) _Float16 f16x2_t;

static __device__ __forceinline__ f16x2_t h2(unsigned u){ return __builtin_bit_cast(f16x2_t, u); }
static __device__ __forceinline__ unsigned h2u(f16x2_t v){ return __builtin_bit_cast(unsigned, v); }
static __device__ __forceinline__ unsigned packh2(float x, float y){
  unsigned short bx = __builtin_bit_cast(unsigned short, (_Float16)x);
  unsigned short by = __builtin_bit_cast(unsigned short, (_Float16)y);
  return (unsigned)bx | ((unsigned)by << 16);
}
static __device__ __forceinline__ f16x2_t pkfma16(f16x2_t a, f16x2_t b, f16x2_t c){
  return __builtin_elementwise_fma(a, b, c);     // -> v_pk_fma_f16 (full rate)
}
static __device__ __forceinline__ f16x2_t splat_l(f16x2_t p){ return __builtin_shufflevector(p, p, 0, 0); }
static __device__ __forceinline__ f16x2_t splat_h(f16x2_t p){ return __builtin_shufflevector(p, p, 1, 1); }

static __device__ __forceinline__ unsigned short f2bf(float f){
  unsigned u = __float_as_uint(f);
  unsigned r = u + 0x7fffu + ((u >> 16) & 1u);   // round-to-nearest-even
  return (unsigned short)(r >> 16);
}
static __device__ __forceinline__ float ftanh(float x){
  float e = __expf(2.f*x);
  return 1.f - 2.f*__builtin_amdgcn_rcpf(e+1.f);
}
static __device__ __forceinline__ float fsigm(float x){
  return __builtin_amdgcn_rcpf(1.f+__expf(-x));
}

// K0: prep — [0,1001): eaTab; [1001,1005): corrH; [1005,1012): WpFrag+pwPad;
// [1012,1263): hq.  (r13 final: simple RPB=2 EA loop — depth-8 pipeline and
// MFMA rewrite both failed to beat it; merged-grid LDS footprint lesson in
// the session journal.)
__global__ __launch_bounds__(256) void k_prep1(
    const float* __restrict__ qaw,
    const float* __restrict__ ew, const float* __restrict__ eb,
    const float* __restrict__ aw, const float* __restrict__ ab,
    unsigned* __restrict__ eaTab,
    const float* __restrict__ qw, const float* __restrict__ mk,
    unsigned* __restrict__ corrH,
    const float* __restrict__ rw, const float* __restrict__ rb,
    const float* __restrict__ pw,
    unsigned short* __restrict__ WpFrag, float* __restrict__ pwPad,
    float* __restrict__ hq){
  __shared__ float qa[RPB*DV_];
  int blk = blockIdx.x;
  if(blk < NB_EA){
    int row0 = blk*RPB;
    for(int i=threadIdx.x; i<RPB*DV_; i+=256){
      int r = i/DV_, cc = i - r*DV_;
      int row = row0 + r;
      qa[i] = (row <= 2*NQ_) ? qaw[row*DV_+cc] : 0.f;
    }
    __syncthreads();
    int d = threadIdx.x;
    if(d >= DV_) return;
    float accE[RPB], accA[RPB];
    #pragma unroll
    for(int r=0;r<RPB;++r){ accE[r] = eb[d]; accA[r] = ab[d]; }
    float we0 = ew[d], wa0 = aw[d];
    for(int j=0;j<DV_;++j){
      int jn = (j+1 < DV_) ? j+1 : j;
      float we1 = ew[jn*DV_+d];
      float wa1 = aw[jn*DV_+d];
      #pragma unroll
      for(int r=0;r<RPB;++r){
        float x = qa[r*DV_+j];
        accE[r] = fmaf(x, we0, accE[r]);
        accA[r] = fmaf(x, wa0, accA[r]);
      }
      we0 = we1; wa0 = wa1;
    }
    #pragma unroll
    for(int r=0;r<RPB;++r){
      int row = row0 + r;
      if(row <= 2*NQ_){
        unsigned he = (unsigned)__builtin_bit_cast(unsigned short, (_Float16)fsigm(accE[r]));
        unsigned ha = (unsigned)__builtin_bit_cast(unsigned short, (_Float16)ftanh(accA[r]));
        eaTab[(size_t)row*DV_+d] = he | (ha << 16);
      }
    }
  } else if(blk < NB_EA+NB_CORR){
    int q = (blk-NB_EA)*256 + threadIdx.x;
    if(q > NQ_) return;
    float qv[DK_];
    #pragma unroll
    for(int j=0;j<DK_;++j) qv[j] = qw[q*DK_+j];
    float s[MEM_]; float mx = -1e30f;
    #pragma unroll
    for(int m=0;m<MEM_;++m){
      float acc = 0.f;
      #pragma unroll
      for(int j=0;j<DK_;++j) acc = fmaf(qv[j], mk[m*DK_+j], acc);
      s[m] = acc; mx = fmaxf(mx, acc);
    }
    float sum = 0.f;
    #pragma unroll
    for(int m=0;m<MEM_;++m){ s[m] = __expf(s[m]-mx); sum += s[m]; }
    float inv = __builtin_amdgcn_rcpf(sum);
    #pragma unroll
    for(int i=0;i<MEM_/2;++i)
      corrH[q*CORR_STRIDE+i] = packh2(s[2*i]*inv, s[2*i+1]*inv);
  } else if(blk < NB_EA+NB_CORR+NB_WPACK){
    int ks = blk - (NB_EA+NB_CORR);
    int nt = threadIdx.x >> 6;
    int lane = threadIdx.x & 63;
    int quad = lane >> 4, col = lane & 15;
    int n = nt*16 + col;
    unsigned short tmp[8];
    #pragma unroll
    for(int j=0;j<8;++j){
      int k = ks*32 + quad*8 + j;
      tmp[j] = (k < DV_ && n < FC_) ? f2bf(rw[k*FC_+n]) : (unsigned short)0;
    }
    uint4* dst = reinterpret_cast<uint4*>(WpFrag + ((size_t)(ks*4+nt)*64 + lane)*8);
    *dst = *reinterpret_cast<const uint4*>(tmp);
    if(ks == 0 && threadIdx.x < 64)
      pwPad[threadIdx.x] = (threadIdx.x < FC_) ? pw[threadIdx.x] : 0.f;
  } else {
    int idx = (blk-(NB_EA+NB_CORR+NB_WPACK))*256 + threadIdx.x;
    int q = idx >> 6, n = idx & 63;
    if(q > NQ_) return;
    float v = 0.f;
    if(n < FC_){
      float acc = rb[n];
      #pragma unroll
      for(int j=0;j<DK_;++j)
        acc = fmaf(qw[q*DK_+j], rw[(DV_+j)*FC_+n], acc);
      v = acc;
    }
    hq[q*64+n] = v;
  }
}

// K1: phase 1 — per-chunk affine (A,B) over 64 steps (CHK=8). Per-step code
// identical to the validated r5 loop. Scan state dies at kernel end — no
// lifetime overlap, no scratch.
__global__ __launch_bounds__(256,8) void k_scanA(const int* __restrict__ qd,
    const int* __restrict__ qad,
    const unsigned* __restrict__ corrH,
    const unsigned* __restrict__ eaTab,
    unsigned* __restrict__ ABu){
  const int blk = blockIdx.x;
  const int b = blk / (CHK-1), c = blk % (CHK-1);
  const int d = threadIdx.x;
  const int dc = (d < DV_) ? d : DV_-1;
  const bool act = (d < DV_);
  const int* __restrict__ qp  = qd  + b*S_ + c*CLEN;
  const int* __restrict__ qap = qad + b*S_ + c*CLEN;

  const f16x2_t one2h = {(_Float16)1.f, (_Float16)1.f};
  f16x2_t A2[MEM_/2], B2[MEM_/2];
  #pragma unroll
  for(int i=0;i<MEM_/2;++i){ A2[i] = one2h; B2[i] = (f16x2_t){(_Float16)0.f,(_Float16)0.f}; }

  unsigned ea0 = eaTab[(size_t)qap[0]*DV_ + dc];
  unsigned ea1 = eaTab[(size_t)qap[1]*DV_ + dc];
  unsigned ea2 = eaTab[(size_t)qap[2]*DV_ + dc];
  int qa3 = qap[3], qa4 = qap[4], qa5 = qap[5];
  int s0 = __builtin_amdgcn_readfirstlane(qp[0]);
  int s1 = __builtin_amdgcn_readfirstlane(qp[1]);
  const unsigned* c0p = corrH + s0*CORR_STRIDE;
  uint4 ca0 = *(const uint4*)(c0p); uint4 cb0 = *(const uint4*)(c0p+4); uint2 cc0 = *(const uint2*)(c0p+8);
  const unsigned* c1p = corrH + s1*CORR_STRIDE;
  uint4 ca1 = *(const uint4*)(c1p); uint4 cb1 = *(const uint4*)(c1p+4); uint2 cc1 = *(const uint2*)(c1p+8);
  int qn2 = qp[2], qn3 = qp[3];

  #pragma unroll 4
  for(int t=0;t<CLEN;++t){
    int qs = __builtin_amdgcn_readfirstlane(qn2);
    const unsigned* cnp = corrH + qs*CORR_STRIDE;
    uint4 ca2 = *(const uint4*)(cnp);
    uint4 cb2 = *(const uint4*)(cnp+4);
    uint2 cc2 = *(const uint2*)(cnp+8);
    unsigned eanew = eaTab[(size_t)qa3*DV_ + dc];
    int t4 = (t+4 < CLEN) ? t+4 : CLEN-1;
    int qnew = qp[t4];
    int t6 = (t+6 < CLEN) ? t+6 : CLEN-1;
    int qanew = qap[t6];

    f16x2_t pe = h2(ea0);
    const f16x2_t ee = splat_l(pe), aa = splat_h(pe);
    #define UPDA(u, i) { \
      f16x2_t cp = h2(u); \
      f16x2_t al = pkfma16(-cp, ee, one2h); \
      f16x2_t be = cp*aa; \
      A2[i] = A2[i]*al; \
      B2[i] = pkfma16(al, B2[i], be); }
    UPDA(ca0.x, 0)  UPDA(ca0.y, 1)  UPDA(ca0.z, 2)  UPDA(ca0.w, 3)
    UPDA(cb0.x, 4)  UPDA(cb0.y, 5)  UPDA(cb0.z, 6)  UPDA(cb0.w, 7)
    UPDA(cc0.x, 8)  UPDA(cc0.y, 9)
    #undef UPDA

    ca0=ca1; cb0=cb1; cc0=cc1;
    ca1=ca2; cb1=cb2; cc1=cc2;
    qn2=qn3; qn3=qnew;
    ea0=ea1; ea1=ea2; ea2=eanew;
    qa3=qa4; qa4=qa5; qa5=qanew;
  }
  if(act){
    unsigned* base = ABu + ((size_t)(b*(CHK-1) + c)*MEM_)*DV_ + d;
    #pragma unroll
    for(int i=0;i<MEM_/2;++i){
      unsigned a01 = h2u(A2[i]);
      unsigned b01 = h2u(B2[i]);
      base[(size_t)(2*i)*DV_]   = (a01 & 0xffffu) | (b01 << 16);
      base[(size_t)(2*i+1)*DV_] = (a01 >> 16)     | (b01 & 0xffff0000u);
    }
  }
}

// K2: prefix — 7 composes (CHK=8).
__global__ __launch_bounds__(256) void k_prefix(const float* __restrict__ mv0,
    const unsigned* __restrict__ ABu, unsigned* __restrict__ Mv0p){
  int i = blockIdx.x*256 + threadIdx.x;
  if(i >= B_*(MEM_/2)*DV_) return;
  int d = i % DV_;
  int p = (i / DV_) % (MEM_/2);
  int b = i / (DV_*(MEM_/2));
  float MvE = mv0[(2*p)*DV_+d];
  float MvO = mv0[(2*p+1)*DV_+d];
  #pragma unroll
  for(int c=1;c<CHK;++c){
    unsigned vE = ABu[((size_t)(b*(CHK-1) + (c-1))*MEM_ + 2*p)*DV_ + d];
    unsigned vO = ABu[((size_t)(b*(CHK-1) + (c-1))*MEM_ + 2*p+1)*DV_ + d];
    MvE = fmaf((float)h2(vE)[0], MvE, (float)h2(vE)[1]);
    MvO = fmaf((float)h2(vO)[0], MvO, (float)h2(vO)[1]);
    Mv0p[((size_t)(b*CHK + c)*(MEM_/2) + p)*DV_ + d] = packh2(MvE, MvO);
  }
}

// K3: fused scan + MFMA (r9 structure, validated r10: WRITE 640KB, no spill).
// Scan all 64 steps into 64-row Xs, then fully-unrolled h=0,1 MFMA pass.
__global__ __launch_bounds__(256,8) void k_scan_mm(const int* __restrict__ qd,
    const int* __restrict__ qad,
    const unsigned* __restrict__ corrH,
    const unsigned* __restrict__ eaTab,
    const float* __restrict__ mv0,
    const unsigned* __restrict__ Mv0p,
    const unsigned short* __restrict__ WpFrag,
    const float* __restrict__ hq,
    const float* __restrict__ pwPad, const float* __restrict__ pb,
    const float* __restrict__ target,
    float* __restrict__ out, float2* __restrict__ partials){
  __shared__ unsigned short Xs[CLEN*XS_STRIDE];   // 29,696 B (64 rows)
  __shared__ float sred[2][2][16];
  __shared__ float sbce[4];

  const int blk = blockIdx.x;
  const int b = blk >> 3, c8 = blk & (CHK-1);
  const int d = threadIdx.x;
  const int dc = (d < DV_) ? d : DV_-1;
  const bool act = (d < DV_);
  const bool padw = (d < 224);
  const int* __restrict__ qp  = qd  + b*S_ + c8*CLEN;
  const int* __restrict__ qap = qad + b*S_ + c8*CLEN;

  const int wave = threadIdx.x >> 6;
  const int lane = threadIdx.x & 63;
  const int col  = lane & 15, quad = lane >> 4;
  const int rt   = wave & 1;
  const int nh   = wave >> 1;
  const int mbase = rt*16;

  f16x2_t Mv2[MEM_/2];
  if(c8 == 0){
    #pragma unroll
    for(int i=0;i<MEM_/2;++i)
      Mv2[i] = (f16x2_t){ (_Float16)mv0[(2*i)*DV_+dc], (_Float16)mv0[(2*i+1)*DV_+dc] };
  } else {
    const unsigned* base = Mv0p + ((size_t)(b*CHK + c8)*(MEM_/2))*DV_ + dc;
    #pragma unroll
    for(int i=0;i<MEM_/2;++i)
      Mv2[i] = h2(base[(size_t)i*DV_]);
  }

  // ---- single 64-step scan (r5 per-step code, primed once) ----
  unsigned ea0 = eaTab[(size_t)qap[0]*DV_ + dc];
  unsigned ea1 = eaTab[(size_t)qap[1]*DV_ + dc];
  unsigned ea2 = eaTab[(size_t)qap[2]*DV_ + dc];
  int qa3 = qap[3], qa4 = qap[4], qa5 = qap[5];
  int s0 = __builtin_amdgcn_readfirstlane(qp[0]);
  int s1 = __builtin_amdgcn_readfirstlane(qp[1]);
  const unsigned* c0p = corrH + s0*CORR_STRIDE;
  uint4 ca0 = *(const uint4*)(c0p); uint4 cb0 = *(const uint4*)(c0p+4); uint2 cc0 = *(const uint2*)(c0p+8);
  const unsigned* c1p = corrH + s1*CORR_STRIDE;
  uint4 ca1 = *(const uint4*)(c1p); uint4 cb1 = *(const uint4*)(c1p+4); uint2 cc1 = *(const uint2*)(c1p+8);
  int qn2 = qp[2], qn3 = qp[3];

  #pragma unroll 4
  for(int t=0;t<CLEN;++t){
    int qs = __builtin_amdgcn_readfirstlane(qn2);
    const unsigned* cnp = corrH + qs*CORR_STRIDE;
    uint4 ca2 = *(const uint4*)(cnp);
    uint4 cb2 = *(const uint4*)(cnp+4);
    uint2 cc2 = *(const uint2*)(cnp+8);
    unsigned eanew = eaTab[(size_t)qa3*DV_ + dc];
    int t4 = (t+4 < CLEN) ? t+4 : CLEN-1;
    int qnew = qp[t4];
    int t6 = (t+6 < CLEN) ? t+6 : CLEN-1;
    int qanew = qap[t6];

    f16x2_t pe = h2(ea0);
    const f16x2_t ee = splat_l(pe), aa = splat_h(pe);
    float rd0 = 0.f, rd1 = 0.f;
    #define UPD2(u, i, acc) { \
      f16x2_t cp = h2(u); \
      acc = __builtin_amdgcn_fdot2(cp, Mv2[i], acc, false); \
      f16x2_t tt = pkfma16(-Mv2[i], ee, aa); \
      Mv2[i] = pkfma16(cp, tt, Mv2[i]); }
    UPD2(ca0.x, 0, rd0)  UPD2(ca0.y, 1, rd1)  UPD2(ca0.z, 2, rd0)  UPD2(ca0.w, 3, rd1)
    UPD2(cb0.x, 4, rd0)  UPD2(cb0.y, 5, rd1)  UPD2(cb0.z, 6, rd0)  UPD2(cb0.w, 7, rd1)
    UPD2(cc0.x, 8, rd0)  UPD2(cc0.y, 9, rd1)
    #undef UPD2

    if(padw) Xs[t*XS_STRIDE + d] = act ? f2bf(rd0+rd1) : (unsigned short)0;

    ca0=ca1; cb0=cb1; cc0=cc1;
    ca1=ca2; cb1=cb2; cc1=cc2;
    qn2=qn3; qn3=qnew;
    ea0=ea1; ea1=ea2; ea2=eanew;
    qa3=qa4; qa4=qa5; qa5=qanew;
  }
  __syncthreads();
  // ---- scan state dead here; MFMA phases follow ----

  float bceAcc = 0.f, cntAcc = 0.f;
  const float pbv = pb[0];

  #pragma unroll
  for(int h=0;h<2;++h){              // compile-time h (fully unrolled)
    const int g0 = h*HLEN;

    int qpre[4];
    #pragma unroll
    for(int reg=0;reg<4;++reg) qpre[reg] = qp[g0 + mbase + quad*4 + reg];
    float hqv[4][2];
    #pragma unroll
    for(int reg=0;reg<4;++reg)
      #pragma unroll
      for(int j=0;j<2;++j)
        hqv[reg][j] = hq[qpre[reg]*64 + (nh*2+j)*16 + col];

    f32x4_t acc[2];
    acc[0] = (f32x4_t){0.f,0.f,0.f,0.f};
    acc[1] = (f32x4_t){0.f,0.f,0.f,0.f};
    #pragma unroll
    for(int ks=0;ks<NKS;++ks){
      bf16x8_t a = *reinterpret_cast<const bf16x8_t*>(Xs + (g0 + mbase + col)*XS_STRIDE + quad*8 + ks*32);
      #pragma unroll
      for(int j=0;j<2;++j){
        int nt = nh*2 + j;
        bf16x8_t bfr = *reinterpret_cast<const bf16x8_t*>(WpFrag + ((size_t)(ks*4+nt)*64 + lane)*8);
        acc[j] = __builtin_amdgcn_mfma_f32_16x16x32_bf16(a, bfr, acc[j], 0, 0, 0);
      }
    }

    float part[4];
    #pragma unroll
    for(int reg=0;reg<4;++reg){
      float s = 0.f;
      #pragma unroll
      for(int j=0;j<2;++j){
        int n = (nh*2+j)*16 + col;
        float hh = acc[j][reg] + hqv[reg][j];
        s = fmaf(pwPad[n], ftanh(hh), s);
      }
      part[reg] = s;
    }
    #pragma unroll
    for(int off=1; off<16; off<<=1){
      #pragma unroll
      for(int reg=0;reg<4;++reg) part[reg] += __shfl_xor(part[reg], off, 64);
    }
    if(col == 0){
      #pragma unroll
      for(int reg=0;reg<4;++reg) sred[rt][nh][quad*4+reg] = part[reg];
    }
    __syncthreads();

    if(nh == 0 && col == 0){
      #pragma unroll
      for(int reg=0;reg<4;++reg){
        int idx = quad*4 + reg;
        int mloc = mbase + idx;
        int row = b*S_ + c8*CLEN + g0 + mloc;
        float logit = sred[rt][0][idx] + sred[rt][1][idx] + pbv;
        out[1+row] = fsigm(logit);
        float t = target[row];
        if(t >= 0.f){
          cntAcc += 1.f;
          bceAcc += fmaxf(logit,0.f) - logit*t + log1pf(__expf(-fabsf(logit)));
        }
      }
    }
    __syncthreads();                 // sred safe for next half's writers
  }

  bceAcc += __shfl_xor(bceAcc, 16, 64); cntAcc += __shfl_xor(cntAcc, 16, 64);
  bceAcc += __shfl_xor(bceAcc, 32, 64); cntAcc += __shfl_xor(cntAcc, 32, 64);
  if(lane == 0 && nh == 0){ sbce[wave] = bceAcc; sbce[2+wave] = cntAcc; }
  __syncthreads();
  if(threadIdx.x == 0)
    partials[blk] = make_float2(sbce[0]+sbce[1], sbce[2]+sbce[3]);
}

// K4: reduce per-block partials -> loss
__global__ __launch_bounds__(256) void k_fin(const float2* __restrict__ partials,
                                             float* __restrict__ out){
  float bce = 0.f, cnt = 0.f;
  for(int i=threadIdx.x; i<MM_BLOCKS; i+=256){
    float2 p = partials[i];
    bce += p.x; cnt += p.y;
  }
  #pragma unroll
  for(int off=32; off>0; off>>=1){
    bce += __shfl_down(bce, off, 64);
    cnt += __shfl_down(cnt, off, 64);
  }
  __shared__ float sb[4], sc[4];
  int w = threadIdx.x >> 6;
  if((threadIdx.x & 63) == 0){ sb[w] = bce; sc[w] = cnt; }
  __syncthreads();
  if(threadIdx.x == 0){
    float Bt = sb[0]+sb[1]+sb[2]+sb[3];
    float Ct = sc[0]+sc[1]+sc[2]+sc[3];
    out[0] = Bt / fmaxf(Ct, 1.f);
  }
}

extern "C" void kernel_launch(void* const* d_in, const int* in_sizes, int n_in,
                              void* d_out, int out_size, void* d_ws, size_t ws_size,
                              hipStream_t stream){
  const int*   qd     = (const int*)d_in[0];
  const int*   qad    = (const int*)d_in[1];
  const float* target = (const float*)d_in[2];
  const float* qw     = (const float*)d_in[3];
  const float* qaw    = (const float*)d_in[4];
  const float* mk     = (const float*)d_in[5];
  const float* mv0    = (const float*)d_in[6];
  const float* ew     = (const float*)d_in[7];
  const float* eb     = (const float*)d_in[8];
  const float* aw     = (const float*)d_in[9];
  const float* ab     = (const float*)d_in[10];
  const float* rw     = (const float*)d_in[11];
  const float* rb     = (const float*)d_in[12];
  const float* pw     = (const float*)d_in[13];
  const float* pb     = (const float*)d_in[14];
  float* out = (float*)d_out;

  char* ws = (char*)d_ws;
  size_t off = 0;
  float2* partials = (float2*)(ws + off);            off += (size_t)MM_BLOCKS*8;
  unsigned* corrH = (unsigned*)(ws + off);           off += (((size_t)(NQ_+1)*CORR_STRIDE*4 + 255)/256)*256;
  unsigned* eaTab = (unsigned*)(ws + off);           off += (((size_t)(2*NQ_+1)*DV_*4 + 255)/256)*256;
  unsigned* ABu   = (unsigned*)(ws + off);           off += (size_t)SCANA_BLOCKS*MEM_*DV_*4;
  unsigned* Mv0p  = (unsigned*)(ws + off);           off += (size_t)MM_BLOCKS*(MEM_/2)*DV_*4;
  unsigned short* WpFrag = (unsigned short*)(ws + off); off += ((size_t)NKS*4*64*8*2 + 255)/256*256;
  float* pwPad    = (float*)(ws + off);              off += 256;
  float* hq       = (float*)(ws + off);              off += (size_t)(NQ_+1)*64*4;

  k_prep1<<<dim3(PREP_BLOCKS), dim3(256), 0, stream>>>(qaw, ew, eb, aw, ab, eaTab,
                                                       qw, mk, corrH,
                                                       rw, rb, pw, WpFrag, pwPad, hq);
  k_scanA<<<dim3(SCANA_BLOCKS), dim3(256), 0, stream>>>(qd, qad, corrH, eaTab, ABu);
  k_prefix<<<dim3((B_*(MEM_/2)*DV_+255)/256), dim3(256), 0, stream>>>(mv0, ABu, Mv0p);
  k_scan_mm<<<dim3(MM_BLOCKS), dim3(256), 0, stream>>>(qd, qad, corrH, eaTab,
                                                       mv0, Mv0p, WpFrag, hq, pwPad, pb, target, out, partials);
  k_fin<<<dim3(1), dim3(256), 0, stream>>>(partials, out);
}